// Round 8
// baseline (140882.385 us; speedup 1.0000x reference)
//
#include <hip/hip_runtime.h>
#include <math.h>

#define BS 128
#define L 512
#define ENC 512
#define DEC 1024
#define ATTN 512
#define EMB 256
#define VOCAB 128
#define TMAX 128
#define KCAT 1792  // EMB+ENC+DEC
#define G4 4096    // 4*DEC
#define NBLK 512   // persistent grid: 2 blocks/CU x 256 CUs

// ---- workspace layout (float offsets) ----
#define OFF_WE     0ull                       // [BS][ATTN][L]     33554432
#define OFF_WGR    33554432ull                // [G4][KCAT] d-major 7340032
#define OFF_BGR    40894464ull                // [G4] d-major          4096
#define OFF_WOUTT  40898560ull                // [DEC][VOCAB]        131072
#define OFF_WDT    41029632ull                // [DEC][ATTN]         524288
#define OFF_C      41553920ull                // [BS][DEC]           131072
#define OFF_WDEC   41684992ull                // [BS][ATTN]           65536
#define OFF_SC     41750528ull                // [BS][L]              65536
#define OFF_XCAT   41816064ull                // [BS][KCAT]          229376
#define OFF_GPART  42045440ull                // [4][BS][G4]        2097152
// end: 44142592 floats = 176.6 MB

__device__ int g_bar = 0;
__device__ int g_gen = 0;

// branch-free tanh: exp + Newton-refined rcp, ~3e-7 rel err
__device__ __forceinline__ float tanh_fast(float x) {
    float ax = fabsf(x);
    float e = __expf(-2.f * ax);
    float d = 1.f + e;
    float r = __builtin_amdgcn_rcpf(d);
    r = r * (2.f - d * r);
    float t = 1.f - 2.f * e * r;
    return copysignf(t, x);
}

// sense-reversing software grid barrier (device scope)
__device__ __forceinline__ void gbar() {
    __syncthreads();
    if (threadIdx.x == 0) {
        __threadfence();  // release all prior global writes to device scope
        int g = __hip_atomic_load(&g_gen, __ATOMIC_RELAXED, __HIP_MEMORY_SCOPE_AGENT);
        int prev = __hip_atomic_fetch_add(&g_bar, 1, __ATOMIC_ACQ_REL, __HIP_MEMORY_SCOPE_AGENT);
        if (prev == NBLK - 1) {
            __hip_atomic_store(&g_bar, 0, __ATOMIC_RELAXED, __HIP_MEMORY_SCOPE_AGENT);
            __hip_atomic_store(&g_gen, g + 1, __ATOMIC_RELEASE, __HIP_MEMORY_SCOPE_AGENT);
        } else {
            while (__hip_atomic_load(&g_gen, __ATOMIC_ACQUIRE, __HIP_MEMORY_SCOPE_AGENT) == g) {
                __builtin_amdgcn_s_sleep(8);
            }
        }
        __threadfence();  // acquire side: invalidate caches before reading others' data
    }
    __syncthreads();
}

// ---------------- one-time prep: d-major W_gate concat, bias sum, W_out^T, W_dec^T ----------------
__global__ void k_prep(const float* __restrict__ W_ih, const float* __restrict__ W_hh,
                       const float* __restrict__ b_ih, const float* __restrict__ b_hh,
                       const float* __restrict__ W_out, const float* __restrict__ W_dec,
                       float* __restrict__ Wgr, float* __restrict__ bgr,
                       float* __restrict__ WoutT, float* __restrict__ WdT) {
    long i = (long)blockIdx.x * 256 + threadIdx.x;
    if (i < (long)G4 * KCAT) {
        int mp = (int)(i / KCAT), k = (int)(i % KCAT);
        int d = mp >> 2, g = mp & 3;
        int r = g * DEC + d;
        Wgr[i] = (k < EMB + ENC) ? W_ih[(long)r * (EMB + ENC) + k]
                                 : W_hh[(long)r * DEC + (k - (EMB + ENC))];
        return;
    }
    long j = i - (long)G4 * KCAT;
    if (j < G4) {
        int d = (int)(j >> 2), g = (int)(j & 3);
        int r = g * DEC + d;
        bgr[j] = b_ih[r] + b_hh[r];
        return;
    }
    long m = j - G4;
    if (m < (long)DEC * VOCAB) {
        int k = (int)(m / VOCAB), v = (int)(m % VOCAB);
        WoutT[m] = W_out[(long)v * DEC + k];
        return;
    }
    long p = m - (long)DEC * VOCAB;
    if (p < (long)DEC * ATTN) {
        int k = (int)(p / ATTN), a = (int)(p % ATTN);
        WdT[p] = W_dec[(long)a * DEC + k];
    }
}

// ---------------- one-time init: c=0, Xcat=[emb(SOS)|0|0], wdec=b_dec, barrier reset ----------------
__global__ void k_init(const float* __restrict__ emb_table, const float* __restrict__ b_dec,
                       float* __restrict__ c, float* __restrict__ Xcat,
                       float* __restrict__ wdec) {
    long i = (long)blockIdx.x * 256 + threadIdx.x;
    if (i == 0) { g_bar = 0; g_gen = 0; }
    if (i < BS * DEC) { c[i] = 0.f; return; }
    long j = i - BS * DEC;
    if (j < (long)BS * KCAT) {
        int cdx = (int)(j % KCAT);
        Xcat[j] = (cdx < EMB) ? emb_table[cdx] : 0.f;  // SOS = row 0
        return;
    }
    long p = j - (long)BS * KCAT;
    if (p < (long)BS * ATTN) {
        wdec[p] = b_dec[(int)(p % ATTN)];              // h0 = 0
    }
}

// ---------------- weighted_enc[b,a,l] = sum_e W_enc[a,e]*enc[b,e,l] + b_enc[a] ----------------
__global__ __launch_bounds__(256) void k_wenc(const float* __restrict__ W_enc,
                                              const float* __restrict__ b_enc,
                                              const float* __restrict__ enc_out,
                                              float* __restrict__ we) {
    __shared__ float As[16][68];
    __shared__ float Bs[16][68];
    int b = blockIdx.z;
    int a0 = blockIdx.y * 64;
    int l0 = blockIdx.x * 64;
    int t = threadIdx.x;
    int ty = t >> 4, tx = t & 15;
    float acc[4][4] = {};
    for (int e0 = 0; e0 < ENC; e0 += 16) {
        {
            int ar = t >> 2;
            int kg = (t & 3) << 2;
            float4 w4 = *(const float4*)&W_enc[(size_t)(a0 + ar) * ENC + e0 + kg];
            As[kg + 0][ar] = w4.x; As[kg + 1][ar] = w4.y; As[kg + 2][ar] = w4.z; As[kg + 3][ar] = w4.w;
            int er = t >> 4;
            int lg = (t & 15) << 2;
            float4 x4 = *(const float4*)&enc_out[((size_t)b * ENC + e0 + er) * L + l0 + lg];
            *(float4*)&Bs[er][lg] = x4;
        }
        __syncthreads();
        #pragma unroll
        for (int kk = 0; kk < 16; kk++) {
            float4 a4 = *(const float4*)&As[kk][ty * 4];
            float4 x4 = *(const float4*)&Bs[kk][tx * 4];
            float av[4] = {a4.x, a4.y, a4.z, a4.w};
            float xv[4] = {x4.x, x4.y, x4.z, x4.w};
            #pragma unroll
            for (int i = 0; i < 4; i++)
                #pragma unroll
                for (int j = 0; j < 4; j++) acc[i][j] += av[i] * xv[j];
        }
        __syncthreads();
    }
    #pragma unroll
    for (int i = 0; i < 4; i++) {
        float be = b_enc[a0 + ty * 4 + i];
        float4 o = {acc[i][0] + be, acc[i][1] + be, acc[i][2] + be, acc[i][3] + be};
        *(float4*)&we[((size_t)b * ATTN + a0 + ty * 4 + i) * L + l0 + tx * 4] = o;
    }
}

// ---------------- persistent megakernel: 128 steps x 4 phases, sw grid barrier ----------------
struct PArgs {
    const float *we, *Wgr, *bgr, *WoutT, *WdT, *v_e, *b_e, *emb, *b_out, *b_dec, *enc_out;
    float *c, *wdec, *sc, *Xcat, *gpart, *logp, *preds, *attn;
};

__global__ __launch_bounds__(256, 2) void k_persist(PArgs P) {
    __shared__ float wd[ATTN];
    __shared__ float ve[ATTN];
    __shared__ float al[L];
    __shared__ float red[256];
    __shared__ float hs[DEC];
    __shared__ float rv[128];
    __shared__ int ri[128];
    __shared__ float As[16][68];
    __shared__ float Xs[16][68];

    int slot = blockIdx.x;
    int t = threadIdx.x;

    for (int ts = 0; ts < TMAX; ts++) {
        // ======== Phase A: scores (128 b x 4 l-chunks of 128; 2 a-halves) ========
        {
            int b = slot >> 2;
            int l0 = (slot & 3) * 128;
            wd[t] = P.wdec[(size_t)b * ATTN + t];
            wd[t + 256] = P.wdec[(size_t)b * ATTN + t + 256];
            ve[t] = P.v_e[t];
            ve[t + 256] = P.v_e[t + 256];
            __syncthreads();
            int l = l0 + (t & 127);
            int ah = t >> 7;
            const float* p = P.we + ((size_t)b * ATTN + ah * 256) * L + l;
            float acc = 0.f;
            #pragma unroll 8
            for (int a = 0; a < 256; a++) {
                float x = p[(size_t)a * L] + wd[ah * 256 + a];
                acc += ve[ah * 256 + a] * tanh_fast(x);
            }
            if (ah == 1) red[t & 127] = acc;
            __syncthreads();
            if (ah == 0) P.sc[(size_t)b * L + l] = acc + red[t] + P.b_e[0];
        }
        gbar();

        // ======== Phase B: softmax + context (128 b x 4 e-chunks of 128) ========
        {
            int b = slot >> 2, ec = slot & 3;
            float v0 = P.sc[(size_t)b * L + t], v1 = P.sc[(size_t)b * L + t + 256];
            red[t] = fmaxf(v0, v1);
            __syncthreads();
            for (int s = 128; s; s >>= 1) { if (t < s) red[t] = fmaxf(red[t], red[t + s]); __syncthreads(); }
            float m = red[0];
            __syncthreads();
            float e0 = expf(v0 - m), e1 = expf(v1 - m);
            red[t] = e0 + e1;
            __syncthreads();
            for (int s = 128; s; s >>= 1) { if (t < s) red[t] += red[t + s]; __syncthreads(); }
            float inv = 1.f / red[0];
            al[t] = e0 * inv; al[t + 256] = e1 * inv;
            __syncthreads();
            if (ec == 0) {
                float* dst = P.attn + ((size_t)b * TMAX + ts) * L;
                dst[t] = al[t]; dst[t + 256] = al[t + 256];
            }
            int w = t >> 6, lane = t & 63;
            int e = ec * 128 + w * 32 + (lane >> 1);
            int lh = (lane & 1) * 256;
            const float* ep = P.enc_out + ((size_t)b * ENC + e) * L + lh;
            float acc = 0.f;
            #pragma unroll 8
            for (int i = 0; i < 64; i++) {
                float4 x = *(const float4*)&ep[i * 4];
                float4 a4 = *(const float4*)&al[lh + i * 4];
                acc += x.x * a4.x + x.y * a4.y + x.z * a4.z + x.w * a4.w;
            }
            acc += __shfl_xor(acc, 1, 64);
            if ((lane & 1) == 0) P.Xcat[(size_t)b * KCAT + EMB + e] = acc;
        }
        gbar();

        // ======== Phase C: gates partials (64 M x 2 b-halves x 4 K-splits) ========
        {
            int M0 = (slot & 63) * 64;
            int rest = slot >> 6;       // 0..7
            int b0 = (rest & 1) * 64;
            int ks = rest >> 1;         // 0..3
            int kbase = ks * 448, kend = kbase + 448;
            int ty = t >> 4, tx = t & 15;
            int r = t >> 2, kg = (t & 3) << 2;
            float acc[4][4] = {};
            float4 wreg = *(const float4*)&P.Wgr[(size_t)(M0 + r) * KCAT + kbase + kg];
            float4 xreg = *(const float4*)&P.Xcat[(size_t)(b0 + r) * KCAT + kbase + kg];
            for (int k0 = kbase; k0 < kend; k0 += 16) {
                As[kg + 0][r] = wreg.x; As[kg + 1][r] = wreg.y; As[kg + 2][r] = wreg.z; As[kg + 3][r] = wreg.w;
                Xs[kg + 0][r] = xreg.x; Xs[kg + 1][r] = xreg.y; Xs[kg + 2][r] = xreg.z; Xs[kg + 3][r] = xreg.w;
                __syncthreads();
                if (k0 + 16 < kend) {
                    wreg = *(const float4*)&P.Wgr[(size_t)(M0 + r) * KCAT + k0 + 16 + kg];
                    xreg = *(const float4*)&P.Xcat[(size_t)(b0 + r) * KCAT + k0 + 16 + kg];
                }
                #pragma unroll
                for (int kk = 0; kk < 16; kk++) {
                    float4 a4 = *(const float4*)&As[kk][ty * 4];
                    float4 x4 = *(const float4*)&Xs[kk][tx * 4];
                    float av[4] = {a4.x, a4.y, a4.z, a4.w};
                    float xv[4] = {x4.x, x4.y, x4.z, x4.w};
                    #pragma unroll
                    for (int i = 0; i < 4; i++)
                        #pragma unroll
                        for (int j = 0; j < 4; j++) acc[i][j] += av[i] * xv[j];
                }
                __syncthreads();
            }
            float* gp = P.gpart + (size_t)ks * BS * G4;
            #pragma unroll
            for (int j = 0; j < 4; j++) {
                float4 o = {acc[0][j], acc[1][j], acc[2][j], acc[3][j]};
                *(float4*)&gp[(size_t)(b0 + tx * 4 + j) * G4 + M0 + ty * 4] = o;
            }
        }
        gbar();

        // ======== Phase D: cell + logits + argmax + emb/h/wdec (slots 0..127) ========
        if (slot < BS) {
            int b = slot;
            #pragma unroll
            for (int q = 0; q < 4; q++) {
                int d = q * 256 + t;
                const float* gp = P.gpart + (size_t)b * G4 + d * 4;
                float4 g = *(const float4*)gp;
                #pragma unroll
                for (int ks = 1; ks < 4; ks++) {
                    float4 p4 = *(const float4*)(gp + (size_t)ks * BS * G4);
                    g.x += p4.x; g.y += p4.y; g.z += p4.z; g.w += p4.w;
                }
                float4 bb = *(const float4*)&P.bgr[(size_t)d * 4];
                float gi = g.x + bb.x, gf = g.y + bb.y, gg = g.z + bb.z, go = g.w + bb.w;
                float fi = 1.f / (1.f + expf(-gi));
                float ff = 1.f / (1.f + expf(-gf));
                float fg = tanhf(gg);
                float fo = 1.f / (1.f + expf(-go));
                size_t ix = (size_t)b * DEC + d;
                float cn = ff * P.c[ix] + fi * fg;
                float hn = fo * tanhf(cn);
                P.c[ix] = cn;
                hs[d] = hn;
                P.Xcat[(size_t)b * KCAT + EMB + ENC + d] = hn;
            }
            __syncthreads();
            int v = t & 127, kh = t >> 7;
            const float* wp = P.WoutT + (size_t)kh * 512 * VOCAB + v;
            float acc = 0.f;
            #pragma unroll 8
            for (int k = 0; k < 512; k++) acc += wp[(size_t)k * VOCAB] * hs[kh * 512 + k];
            red[t] = acc;
            __syncthreads();
            float logits = 0.f;
            if (t < 128) {
                logits = red[t] + red[t + 128] + P.b_out[t];
                rv[t] = logits; ri[t] = t;
            }
            __syncthreads();
            for (int s = 64; s; s >>= 1) {
                if (t < s) {
                    float ov = rv[t + s]; int oi = ri[t + s];
                    if (ov > rv[t] || (ov == rv[t] && oi < ri[t])) { rv[t] = ov; ri[t] = oi; }
                }
                __syncthreads();
            }
            float m = rv[0]; int am = ri[0];
            __syncthreads();
            if (t < 128) red[t] = expf(logits - m);
            __syncthreads();
            for (int s = 64; s; s >>= 1) { if (t < s && t + s < 128) red[t] += red[t + s]; __syncthreads(); }
            if (t < 128) P.logp[((size_t)b * TMAX + ts) * VOCAB + t] = logits - m - logf(red[0]);
            if (t == 0) P.preds[(size_t)b * TMAX + ts] = (float)am;
            P.Xcat[(size_t)b * KCAT + t] = P.emb[(size_t)am * EMB + t];
            #pragma unroll
            for (int a2 = 0; a2 < 2; a2++) {
                int a = t + a2 * 256;
                const float* wdp = P.WdT + a;
                float s = 0.f;
                #pragma unroll 8
                for (int k = 0; k < DEC; k++) s += wdp[(size_t)k * ATTN] * hs[k];
                P.wdec[(size_t)b * ATTN + a] = s + P.b_dec[a];
            }
        }
        gbar();
    }
}

extern "C" void kernel_launch(void* const* d_in, const int* in_sizes, int n_in,
                              void* d_out, int out_size, void* d_ws, size_t ws_size,
                              hipStream_t stream) {
    const float* enc_out = (const float*)d_in[0];
    const float* W_enc   = (const float*)d_in[1];
    const float* b_enc   = (const float*)d_in[2];
    const float* W_dec   = (const float*)d_in[3];
    const float* b_dec   = (const float*)d_in[4];
    const float* v_e     = (const float*)d_in[5];
    const float* b_e     = (const float*)d_in[6];
    const float* emb     = (const float*)d_in[7];
    const float* W_ih    = (const float*)d_in[8];
    const float* W_hh    = (const float*)d_in[9];
    const float* b_ih    = (const float*)d_in[10];
    const float* b_hh    = (const float*)d_in[11];
    const float* W_out   = (const float*)d_in[12];
    const float* b_out   = (const float*)d_in[13];

    float* ws    = (float*)d_ws;
    float* we    = ws + OFF_WE;
    float* Wgr   = ws + OFF_WGR;
    float* bgr   = ws + OFF_BGR;
    float* WoutT = ws + OFF_WOUTT;
    float* WdT   = ws + OFF_WDT;
    float* c     = ws + OFF_C;
    float* wdec  = ws + OFF_WDEC;
    float* sc    = ws + OFF_SC;
    float* Xcat  = ws + OFF_XCAT;
    float* gpart = ws + OFF_GPART;

    float* logp_out  = (float*)d_out;
    float* preds_out = logp_out + (size_t)BS * TMAX * VOCAB;
    float* attn_out  = preds_out + (size_t)BS * TMAX;

    {
        long n = (long)G4 * KCAT + G4 + (long)DEC * VOCAB + (long)DEC * ATTN;
        k_prep<<<(int)((n + 255) / 256), 256, 0, stream>>>(W_ih, W_hh, b_ih, b_hh, W_out, W_dec,
                                                           Wgr, bgr, WoutT, WdT);
    }
    {
        long n = (long)BS * DEC + (long)BS * KCAT + (long)BS * ATTN;
        k_init<<<(int)((n + 255) / 256), 256, 0, stream>>>(emb, b_dec, c, Xcat, wdec);
    }
    k_wenc<<<dim3(8, 8, 128), 256, 0, stream>>>(W_enc, b_enc, enc_out, we);

    PArgs P;
    P.we = we; P.Wgr = Wgr; P.bgr = bgr; P.WoutT = WoutT; P.WdT = WdT;
    P.v_e = v_e; P.b_e = b_e; P.emb = emb; P.b_out = b_out; P.b_dec = b_dec;
    P.enc_out = enc_out;
    P.c = c; P.wdec = wdec; P.sc = sc; P.Xcat = Xcat; P.gpart = gpart;
    P.logp = logp_out; P.preds = preds_out; P.attn = attn_out;
    k_persist<<<NBLK, 256, 0, stream>>>(P);
}

// Round 9
// 41934.955 us; speedup vs baseline: 3.3595x; 3.3595x over previous
//
#include <hip/hip_runtime.h>
#include <math.h>

#define BS 128
#define L 512
#define ENC 512
#define DEC 1024
#define ATTN 512
#define EMB 256
#define VOCAB 128
#define TMAX 128
#define KCAT 1792  // EMB+ENC+DEC
#define G4 4096    // 4*DEC
#define NBLK 512   // persistent grid: 2 blocks/CU x 256 CUs
#define NGRP 64    // barrier groups (8 blocks each)

// ---- workspace layout (float offsets) ----
#define OFF_WE     0ull                       // [BS][ATTN][L]     33554432
#define OFF_WGR    33554432ull                // [G4][KCAT] d-major 7340032
#define OFF_BGR    40894464ull                // [G4] d-major          4096
#define OFF_WOUTT  40898560ull                // [DEC][VOCAB]        131072
#define OFF_WDT    41029632ull                // [DEC][ATTN]         524288
#define OFF_C      41553920ull                // [BS][DEC]           131072
#define OFF_WDEC   41684992ull                // [BS][ATTN]           65536
#define OFF_SC     41750528ull                // [BS][L]              65536
#define OFF_XCAT   41816064ull                // [BS][KCAT]          229376
#define OFF_GPART  42045440ull                // [4][BS][G4]        2097152
// end: 44142592 floats = 176.6 MB

// ---- software grid barrier state (monotonic, hierarchical) ----
__device__ int g_grp[NGRP * 16];  // 64B-strided group counters
__device__ int g_top;
__device__ int g_gen;

// branch-free tanh: exp + Newton-refined rcp, ~3e-7 rel err
__device__ __forceinline__ float tanh_fast(float x) {
    float ax = fabsf(x);
    float e = __expf(-2.f * ax);
    float d = 1.f + e;
    float r = __builtin_amdgcn_rcpf(d);
    r = r * (2.f - d * r);
    float t = 1.f - 2.f * e * r;
    return copysignf(t, x);
}

// hierarchical monotonic grid barrier: relaxed spin + single acquire
__device__ __forceinline__ void gbar(int nb, int bid) {
    __syncthreads();
    if (threadIdx.x == 0) {
        int grp = bid >> 3;  // 8 blocks per group
        int prev = __hip_atomic_fetch_add(&g_grp[grp * 16], 1,
                                          __ATOMIC_ACQ_REL, __HIP_MEMORY_SCOPE_AGENT);
        if (prev == nb * 8 + 7) {  // last of group
            int p2 = __hip_atomic_fetch_add(&g_top, 1,
                                            __ATOMIC_ACQ_REL, __HIP_MEMORY_SCOPE_AGENT);
            if (p2 == nb * NGRP + (NGRP - 1)) {  // last group
                __hip_atomic_store(&g_gen, nb + 1,
                                   __ATOMIC_RELEASE, __HIP_MEMORY_SCOPE_AGENT);
            }
        }
        // relaxed spin: no cache maintenance per poll
        while (__hip_atomic_load(&g_gen, __ATOMIC_RELAXED, __HIP_MEMORY_SCOPE_AGENT) <= nb) {
            __builtin_amdgcn_s_sleep(32);
        }
        // single acquire: pull in remote writes once
        (void)__hip_atomic_load(&g_gen, __ATOMIC_ACQUIRE, __HIP_MEMORY_SCOPE_AGENT);
    }
    __syncthreads();
}

// ---------------- one-time prep: d-major W_gate concat, bias sum, W_out^T, W_dec^T ----------------
__global__ void k_prep(const float* __restrict__ W_ih, const float* __restrict__ W_hh,
                       const float* __restrict__ b_ih, const float* __restrict__ b_hh,
                       const float* __restrict__ W_out, const float* __restrict__ W_dec,
                       float* __restrict__ Wgr, float* __restrict__ bgr,
                       float* __restrict__ WoutT, float* __restrict__ WdT) {
    long i = (long)blockIdx.x * 256 + threadIdx.x;
    if (i < (long)G4 * KCAT) {
        int mp = (int)(i / KCAT), k = (int)(i % KCAT);
        int d = mp >> 2, g = mp & 3;
        int r = g * DEC + d;
        Wgr[i] = (k < EMB + ENC) ? W_ih[(long)r * (EMB + ENC) + k]
                                 : W_hh[(long)r * DEC + (k - (EMB + ENC))];
        return;
    }
    long j = i - (long)G4 * KCAT;
    if (j < G4) {
        int d = (int)(j >> 2), g = (int)(j & 3);
        int r = g * DEC + d;
        bgr[j] = b_ih[r] + b_hh[r];
        return;
    }
    long m = j - G4;
    if (m < (long)DEC * VOCAB) {
        int k = (int)(m / VOCAB), v = (int)(m % VOCAB);
        WoutT[m] = W_out[(long)v * DEC + k];
        return;
    }
    long p = m - (long)DEC * VOCAB;
    if (p < (long)DEC * ATTN) {
        int k = (int)(p / ATTN), a = (int)(p % ATTN);
        WdT[p] = W_dec[(long)a * DEC + k];
    }
}

// ---------------- one-time init: c=0, Xcat=[emb(SOS)|0|0], wdec=b_dec, barrier reset ----------------
__global__ void k_init(const float* __restrict__ emb_table, const float* __restrict__ b_dec,
                       float* __restrict__ c, float* __restrict__ Xcat,
                       float* __restrict__ wdec) {
    long i = (long)blockIdx.x * 256 + threadIdx.x;
    if (i == 0) {
        g_top = 0; g_gen = 0;
        for (int q = 0; q < NGRP * 16; q++) g_grp[q] = 0;
    }
    if (i < BS * DEC) { c[i] = 0.f; return; }
    long j = i - BS * DEC;
    if (j < (long)BS * KCAT) {
        int cdx = (int)(j % KCAT);
        Xcat[j] = (cdx < EMB) ? emb_table[cdx] : 0.f;  // SOS = row 0
        return;
    }
    long p = j - (long)BS * KCAT;
    if (p < (long)BS * ATTN) {
        wdec[p] = b_dec[(int)(p % ATTN)];              // h0 = 0
    }
}

// ---------------- weighted_enc[b,a,l] = sum_e W_enc[a,e]*enc[b,e,l] + b_enc[a] ----------------
__global__ __launch_bounds__(256) void k_wenc(const float* __restrict__ W_enc,
                                              const float* __restrict__ b_enc,
                                              const float* __restrict__ enc_out,
                                              float* __restrict__ we) {
    __shared__ float As[16][68];
    __shared__ float Bs[16][68];
    int b = blockIdx.z;
    int a0 = blockIdx.y * 64;
    int l0 = blockIdx.x * 64;
    int t = threadIdx.x;
    int ty = t >> 4, tx = t & 15;
    float acc[4][4] = {};
    for (int e0 = 0; e0 < ENC; e0 += 16) {
        {
            int ar = t >> 2;
            int kg = (t & 3) << 2;
            float4 w4 = *(const float4*)&W_enc[(size_t)(a0 + ar) * ENC + e0 + kg];
            As[kg + 0][ar] = w4.x; As[kg + 1][ar] = w4.y; As[kg + 2][ar] = w4.z; As[kg + 3][ar] = w4.w;
            int er = t >> 4;
            int lg = (t & 15) << 2;
            float4 x4 = *(const float4*)&enc_out[((size_t)b * ENC + e0 + er) * L + l0 + lg];
            *(float4*)&Bs[er][lg] = x4;
        }
        __syncthreads();
        #pragma unroll
        for (int kk = 0; kk < 16; kk++) {
            float4 a4 = *(const float4*)&As[kk][ty * 4];
            float4 x4 = *(const float4*)&Bs[kk][tx * 4];
            float av[4] = {a4.x, a4.y, a4.z, a4.w};
            float xv[4] = {x4.x, x4.y, x4.z, x4.w};
            #pragma unroll
            for (int i = 0; i < 4; i++)
                #pragma unroll
                for (int j = 0; j < 4; j++) acc[i][j] += av[i] * xv[j];
        }
        __syncthreads();
    }
    #pragma unroll
    for (int i = 0; i < 4; i++) {
        float be = b_enc[a0 + ty * 4 + i];
        float4 o = {acc[i][0] + be, acc[i][1] + be, acc[i][2] + be, acc[i][3] + be};
        *(float4*)&we[((size_t)b * ATTN + a0 + ty * 4 + i) * L + l0 + tx * 4] = o;
    }
}

// ---------------- persistent megakernel: 128 steps x 4 phases, sw grid barrier ----------------
struct PArgs {
    const float *we, *Wgr, *bgr, *WoutT, *WdT, *v_e, *b_e, *emb, *b_out, *b_dec, *enc_out;
    float *c, *wdec, *sc, *Xcat, *gpart, *logp, *preds, *attn;
};

__global__ __launch_bounds__(256, 2) void k_persist(PArgs P) {
    __shared__ float wd[ATTN];
    __shared__ float ve[ATTN];
    __shared__ float al[L];
    __shared__ float red[256];
    __shared__ float hs[DEC];
    __shared__ float rv[128];
    __shared__ int ri[128];
    __shared__ float As[16][68];
    __shared__ float Xs[16][68];

    int slot = blockIdx.x;
    int t = threadIdx.x;
    int nb = 0;

    for (int ts = 0; ts < TMAX; ts++) {
        // ======== Phase A: scores (128 b x 4 l-chunks of 128; 2 a-halves) ========
        {
            int b = slot >> 2;
            int l0 = (slot & 3) * 128;
            wd[t] = P.wdec[(size_t)b * ATTN + t];
            wd[t + 256] = P.wdec[(size_t)b * ATTN + t + 256];
            ve[t] = P.v_e[t];
            ve[t + 256] = P.v_e[t + 256];
            __syncthreads();
            int l = l0 + (t & 127);
            int ah = t >> 7;
            const float* p = P.we + ((size_t)b * ATTN + ah * 256) * L + l;
            float acc = 0.f;
            #pragma unroll 8
            for (int a = 0; a < 256; a++) {
                float x = p[(size_t)a * L] + wd[ah * 256 + a];
                acc += ve[ah * 256 + a] * tanh_fast(x);
            }
            if (ah == 1) red[t & 127] = acc;
            __syncthreads();
            if (ah == 0) P.sc[(size_t)b * L + l] = acc + red[t] + P.b_e[0];
        }
        gbar(nb++, slot);

        // ======== Phase B: softmax + context (128 b x 4 e-chunks of 128) ========
        {
            int b = slot >> 2, ec = slot & 3;
            float v0 = P.sc[(size_t)b * L + t], v1 = P.sc[(size_t)b * L + t + 256];
            red[t] = fmaxf(v0, v1);
            __syncthreads();
            for (int s = 128; s; s >>= 1) { if (t < s) red[t] = fmaxf(red[t], red[t + s]); __syncthreads(); }
            float m = red[0];
            __syncthreads();
            float e0 = expf(v0 - m), e1 = expf(v1 - m);
            red[t] = e0 + e1;
            __syncthreads();
            for (int s = 128; s; s >>= 1) { if (t < s) red[t] += red[t + s]; __syncthreads(); }
            float inv = 1.f / red[0];
            al[t] = e0 * inv; al[t + 256] = e1 * inv;
            __syncthreads();
            if (ec == 0) {
                float* dst = P.attn + ((size_t)b * TMAX + ts) * L;
                dst[t] = al[t]; dst[t + 256] = al[t + 256];
            }
            int w = t >> 6, lane = t & 63;
            int e = ec * 128 + w * 32 + (lane >> 1);
            int lh = (lane & 1) * 256;
            const float* ep = P.enc_out + ((size_t)b * ENC + e) * L + lh;
            float acc = 0.f;
            #pragma unroll 8
            for (int i = 0; i < 64; i++) {
                float4 x = *(const float4*)&ep[i * 4];
                float4 a4 = *(const float4*)&al[lh + i * 4];
                acc += x.x * a4.x + x.y * a4.y + x.z * a4.z + x.w * a4.w;
            }
            acc += __shfl_xor(acc, 1, 64);
            if ((lane & 1) == 0) P.Xcat[(size_t)b * KCAT + EMB + e] = acc;
        }
        gbar(nb++, slot);

        // ======== Phase C: gates partials (64 M x 2 b-halves x 4 K-splits) ========
        {
            int M0 = (slot & 63) * 64;
            int rest = slot >> 6;       // 0..7
            int b0 = (rest & 1) * 64;
            int ks = rest >> 1;         // 0..3
            int kbase = ks * 448, kend = kbase + 448;
            int ty = t >> 4, tx = t & 15;
            int r = t >> 2, kg = (t & 3) << 2;
            float acc[4][4] = {};
            float4 wreg = *(const float4*)&P.Wgr[(size_t)(M0 + r) * KCAT + kbase + kg];
            float4 xreg = *(const float4*)&P.Xcat[(size_t)(b0 + r) * KCAT + kbase + kg];
            for (int k0 = kbase; k0 < kend; k0 += 16) {
                As[kg + 0][r] = wreg.x; As[kg + 1][r] = wreg.y; As[kg + 2][r] = wreg.z; As[kg + 3][r] = wreg.w;
                Xs[kg + 0][r] = xreg.x; Xs[kg + 1][r] = xreg.y; Xs[kg + 2][r] = xreg.z; Xs[kg + 3][r] = xreg.w;
                __syncthreads();
                if (k0 + 16 < kend) {
                    wreg = *(const float4*)&P.Wgr[(size_t)(M0 + r) * KCAT + k0 + 16 + kg];
                    xreg = *(const float4*)&P.Xcat[(size_t)(b0 + r) * KCAT + k0 + 16 + kg];
                }
                #pragma unroll
                for (int kk = 0; kk < 16; kk++) {
                    float4 a4 = *(const float4*)&As[kk][ty * 4];
                    float4 x4 = *(const float4*)&Xs[kk][tx * 4];
                    float av[4] = {a4.x, a4.y, a4.z, a4.w};
                    float xv[4] = {x4.x, x4.y, x4.z, x4.w};
                    #pragma unroll
                    for (int i = 0; i < 4; i++)
                        #pragma unroll
                        for (int j = 0; j < 4; j++) acc[i][j] += av[i] * xv[j];
                }
                __syncthreads();
            }
            float* gp = P.gpart + (size_t)ks * BS * G4;
            #pragma unroll
            for (int j = 0; j < 4; j++) {
                float4 o = {acc[0][j], acc[1][j], acc[2][j], acc[3][j]};
                *(float4*)&gp[(size_t)(b0 + tx * 4 + j) * G4 + M0 + ty * 4] = o;
            }
        }
        gbar(nb++, slot);

        // ======== Phase D: cell + logits + argmax + emb/h/wdec (slots 0..127) ========
        if (slot < BS) {
            int b = slot;
            #pragma unroll
            for (int q = 0; q < 4; q++) {
                int d = q * 256 + t;
                const float* gp = P.gpart + (size_t)b * G4 + d * 4;
                float4 g = *(const float4*)gp;
                #pragma unroll
                for (int ks = 1; ks < 4; ks++) {
                    float4 p4 = *(const float4*)(gp + (size_t)ks * BS * G4);
                    g.x += p4.x; g.y += p4.y; g.z += p4.z; g.w += p4.w;
                }
                float4 bb = *(const float4*)&P.bgr[(size_t)d * 4];
                float gi = g.x + bb.x, gf = g.y + bb.y, gg = g.z + bb.z, go = g.w + bb.w;
                float fi = 1.f / (1.f + expf(-gi));
                float ff = 1.f / (1.f + expf(-gf));
                float fg = tanhf(gg);
                float fo = 1.f / (1.f + expf(-go));
                size_t ix = (size_t)b * DEC + d;
                float cn = ff * P.c[ix] + fi * fg;
                float hn = fo * tanhf(cn);
                P.c[ix] = cn;
                hs[d] = hn;
                P.Xcat[(size_t)b * KCAT + EMB + ENC + d] = hn;
            }
            __syncthreads();
            int v = t & 127, kh = t >> 7;
            const float* wp = P.WoutT + (size_t)kh * 512 * VOCAB + v;
            float acc = 0.f;
            #pragma unroll 8
            for (int k = 0; k < 512; k++) acc += wp[(size_t)k * VOCAB] * hs[kh * 512 + k];
            red[t] = acc;
            __syncthreads();
            float logits = 0.f;
            if (t < 128) {
                logits = red[t] + red[t + 128] + P.b_out[t];
                rv[t] = logits; ri[t] = t;
            }
            __syncthreads();
            for (int s = 64; s; s >>= 1) {
                if (t < s) {
                    float ov = rv[t + s]; int oi = ri[t + s];
                    if (ov > rv[t] || (ov == rv[t] && oi < ri[t])) { rv[t] = ov; ri[t] = oi; }
                }
                __syncthreads();
            }
            float m = rv[0]; int am = ri[0];
            __syncthreads();
            if (t < 128) red[t] = expf(logits - m);
            __syncthreads();
            for (int s = 64; s; s >>= 1) { if (t < s && t + s < 128) red[t] += red[t + s]; __syncthreads(); }
            if (t < 128) P.logp[((size_t)b * TMAX + ts) * VOCAB + t] = logits - m - logf(red[0]);
            if (t == 0) P.preds[(size_t)b * TMAX + ts] = (float)am;
            P.Xcat[(size_t)b * KCAT + t] = P.emb[(size_t)am * EMB + t];
            #pragma unroll
            for (int a2 = 0; a2 < 2; a2++) {
                int a = t + a2 * 256;
                const float* wdp = P.WdT + a;
                float s = 0.f;
                #pragma unroll 8
                for (int k = 0; k < DEC; k++) s += wdp[(size_t)k * ATTN] * hs[k];
                P.wdec[(size_t)b * ATTN + a] = s + P.b_dec[a];
            }
        }
        gbar(nb++, slot);
    }
}

extern "C" void kernel_launch(void* const* d_in, const int* in_sizes, int n_in,
                              void* d_out, int out_size, void* d_ws, size_t ws_size,
                              hipStream_t stream) {
    const float* enc_out = (const float*)d_in[0];
    const float* W_enc   = (const float*)d_in[1];
    const float* b_enc   = (const float*)d_in[2];
    const float* W_dec   = (const float*)d_in[3];
    const float* b_dec   = (const float*)d_in[4];
    const float* v_e     = (const float*)d_in[5];
    const float* b_e     = (const float*)d_in[6];
    const float* emb     = (const float*)d_in[7];
    const float* W_ih    = (const float*)d_in[8];
    const float* W_hh    = (const float*)d_in[9];
    const float* b_ih    = (const float*)d_in[10];
    const float* b_hh    = (const float*)d_in[11];
    const float* W_out   = (const float*)d_in[12];
    const float* b_out   = (const float*)d_in[13];

    float* ws    = (float*)d_ws;
    float* we    = ws + OFF_WE;
    float* Wgr   = ws + OFF_WGR;
    float* bgr   = ws + OFF_BGR;
    float* WoutT = ws + OFF_WOUTT;
    float* WdT   = ws + OFF_WDT;
    float* c     = ws + OFF_C;
    float* wdec  = ws + OFF_WDEC;
    float* sc    = ws + OFF_SC;
    float* Xcat  = ws + OFF_XCAT;
    float* gpart = ws + OFF_GPART;

    float* logp_out  = (float*)d_out;
    float* preds_out = logp_out + (size_t)BS * TMAX * VOCAB;
    float* attn_out  = preds_out + (size_t)BS * TMAX;

    {
        long n = (long)G4 * KCAT + G4 + (long)DEC * VOCAB + (long)DEC * ATTN;
        k_prep<<<(int)((n + 255) / 256), 256, 0, stream>>>(W_ih, W_hh, b_ih, b_hh, W_out, W_dec,
                                                           Wgr, bgr, WoutT, WdT);
    }
    {
        long n = (long)BS * DEC + (long)BS * KCAT + (long)BS * ATTN;
        k_init<<<(int)((n + 255) / 256), 256, 0, stream>>>(emb, b_dec, c, Xcat, wdec);
    }
    k_wenc<<<dim3(8, 8, 128), 256, 0, stream>>>(W_enc, b_enc, enc_out, we);

    PArgs P;
    P.we = we; P.Wgr = Wgr; P.bgr = bgr; P.WoutT = WoutT; P.WdT = WdT;
    P.v_e = v_e; P.b_e = b_e; P.emb = emb; P.b_out = b_out; P.b_dec = b_dec;
    P.enc_out = enc_out;
    P.c = c; P.wdec = wdec; P.sc = sc; P.Xcat = Xcat; P.gpart = gpart;
    P.logp = logp_out; P.preds = preds_out; P.attn = attn_out;
    k_persist<<<NBLK, 256, 0, stream>>>(P);
}